// Round 5
// baseline (340.133 us; speedup 1.0000x reference)
//
#include <hip/hip_runtime.h>

#define IN_F 64
#define OUT_F 64
#define WPAD 65   // padded LDS stride: 2-way bank aliasing = free both directions

// ===========================================================================
// CSR-build path: counting sort by dst, then per-node gather (no fp atomics).
// ===========================================================================

// K1: degree histogram (4 edges/thread, int4 loads)
__global__ __launch_bounds__(256) void deg_hist_kernel(
    const int* __restrict__ dst, int* __restrict__ cnt, int nE)
{
    int i = blockIdx.x * blockDim.x + threadIdx.x;
    int e0 = i * 4;
    if (e0 + 3 < nE) {
        int4 d = *reinterpret_cast<const int4*>(dst + e0);
        atomicAdd(cnt + d.x, 1); atomicAdd(cnt + d.y, 1);
        atomicAdd(cnt + d.z, 1); atomicAdd(cnt + d.w, 1);
    } else {
        for (int e = e0; e < nE; ++e) atomicAdd(cnt + dst[e], 1);
    }
}

// K2a: per-block exclusive scan (1024 elems/block), block totals -> partials
__global__ __launch_bounds__(1024) void scan_block_kernel(
    int* __restrict__ c, int* __restrict__ partials, int nN)
{
    __shared__ int buf[1024];
    int t = threadIdx.x;
    int gid = blockIdx.x * 1024 + t;
    int v = (gid < nN) ? c[gid] : 0;
    buf[t] = v;
    __syncthreads();
    for (int off = 1; off < 1024; off <<= 1) {
        int u = (t >= off) ? buf[t - off] : 0;
        __syncthreads();
        buf[t] += u;
        __syncthreads();
    }
    if (gid < nN) c[gid] = buf[t] - v;            // exclusive
    if (t == 1023) partials[blockIdx.x] = buf[t]; // inclusive block total
}

// K2b: single-block exclusive scan of partials (nP <= 1024)
__global__ __launch_bounds__(1024) void scan_partials_kernel(
    int* __restrict__ p, int nP)
{
    __shared__ int buf[1024];
    int t = threadIdx.x;
    int v = (t < nP) ? p[t] : 0;
    buf[t] = v;
    __syncthreads();
    for (int off = 1; off < 1024; off <<= 1) {
        int u = (t >= off) ? buf[t - off] : 0;
        __syncthreads();
        buf[t] += u;
        __syncthreads();
    }
    if (t < nP) p[t] = buf[t] - v;
}

// K2c: add scanned block offsets back
__global__ __launch_bounds__(1024) void scan_add_kernel(
    int* __restrict__ c, const int* __restrict__ p, int nN)
{
    int gid = blockIdx.x * 1024 + threadIdx.x;
    if (gid < nN) c[gid] += p[blockIdx.x];
}

// K3: scatter edges into CSR slots (4 edges/thread, vector loads);
// cursor ends as inclusive ends (cursor[n] == offs[n+1]).
__global__ __launch_bounds__(256) void scatter_kernel(
    const int* __restrict__ src, const int* __restrict__ dst,
    const float* __restrict__ ef, int* __restrict__ cursor,
    int2* __restrict__ csr, int nE)
{
    int i = blockIdx.x * blockDim.x + threadIdx.x;
    int e0 = i * 4;
    if (e0 + 3 < nE) {
        int4   s = *reinterpret_cast<const int4*>(src + e0);
        int4   d = *reinterpret_cast<const int4*>(dst + e0);
        float4 w = *reinterpret_cast<const float4*>(ef + e0);
        int p0 = atomicAdd(cursor + d.x, 1); csr[p0] = make_int2(s.x, __float_as_int(w.x));
        int p1 = atomicAdd(cursor + d.y, 1); csr[p1] = make_int2(s.y, __float_as_int(w.y));
        int p2 = atomicAdd(cursor + d.z, 1); csr[p2] = make_int2(s.z, __float_as_int(w.z));
        int p3 = atomicAdd(cursor + d.w, 1); csr[p3] = make_int2(s.w, __float_as_int(w.w));
    } else {
        for (int e = e0; e < nE; ++e) {
            int d = dst[e];
            int pos = atomicAdd(cursor + d, 1);
            csr[pos] = make_int2(src[e], __float_as_int(ef[e]));
        }
    }
}

// K4: per-node gather + fused dual GEMV. 4 waves/block; each wave owns a
// contiguous chunk of nodes. Weight COLUMNS live in VGPRs, extracted once
// per wave from a padded TRANSPOSED LDS stage:
//   Ws[i*WPAD + o] = W_self[o][i]  =>  wsc[i] = Ws[i*WPAD + lane] = W_self[lane][i]
// (round-3-verified layout; round 4's row-major extraction computed W^T — bug).
// Per node the only LDS traffic is 2 writes + 32 b128 broadcasts + 8 shfl.
__global__ __launch_bounds__(256) void node_fused_kernel(
    const float* __restrict__ feat, const int2* __restrict__ csr,
    const int* __restrict__ cursor,
    const float* __restrict__ W_self, const float* __restrict__ b_self,
    const float* __restrict__ W_neigh, const float* __restrict__ b_neigh,
    float* __restrict__ out, int nN, int chunk)
{
    __shared__ float Ws[IN_F * WPAD];   // Ws[i*WPAD+o] = W_self[o][i]
    __shared__ float Wn[IN_F * WPAD];
    __shared__ float frow[4][IN_F];
    __shared__ float hrow[4][IN_F];

    int tid = threadIdx.x;
    // transposed staging: global read coalesced (i = lane), LDS write banks
    // (i+o)%32 -> 2-way aliasing = free
    for (int idx = tid; idx < IN_F * OUT_F; idx += 256) {
        int o = idx >> 6, i = idx & 63;
        Ws[i * WPAD + o] = W_self[o * IN_F + i];
        Wn[i * WPAD + o] = W_neigh[o * IN_F + i];
    }
    __syncthreads();

    int wave = tid >> 6, lane = tid & 63;

    // per-lane weight columns: wsc[i] = W_self[lane][i]. Consecutive lanes ->
    // consecutive LDS addresses (2-way aliasing = free). Fully unrolled,
    // static indices only -> stays in VGPRs. One-time cost per wave.
    float wsc[IN_F], wnc[IN_F];
    #pragma unroll
    for (int i = 0; i < IN_F; ++i) {
        wsc[i] = Ws[i * WPAD + lane];
        wnc[i] = Wn[i * WPAD + lane];
    }
    float bias = b_self[lane] + b_neigh[lane];

    int wid = blockIdx.x * 4 + wave;
    int n0 = wid * chunk;
    int n1 = min(n0 + chunk, nN);
    int g = lane >> 4;       // 16-lane edge group 0..3
    int sub = lane & 15;     // float4 slot: features 4*sub..4*sub+3

    for (int n = n0; n < n1; ++n) {
        int start = (n == 0) ? 0 : cursor[n - 1];
        int end   = cursor[n];
        float f = feat[(size_t)n * IN_F + lane];   // issued early, used late

        float ax = 0.f, ay = 0.f, az = 0.f, aw = 0.f;
        int e = start + g;
        // main: 4 edges per lane in flight (16 edges per wave superstep)
        for (; e + 12 < end; e += 16) {
            int2 p0 = csr[e];
            int2 p1 = csr[e + 4];
            int2 p2 = csr[e + 8];
            int2 p3 = csr[e + 12];
            const float4 v0 = *reinterpret_cast<const float4*>(feat + (size_t)p0.x * IN_F + sub * 4);
            const float4 v1 = *reinterpret_cast<const float4*>(feat + (size_t)p1.x * IN_F + sub * 4);
            const float4 v2 = *reinterpret_cast<const float4*>(feat + (size_t)p2.x * IN_F + sub * 4);
            const float4 v3 = *reinterpret_cast<const float4*>(feat + (size_t)p3.x * IN_F + sub * 4);
            float w0 = __int_as_float(p0.y), w1 = __int_as_float(p1.y);
            float w2 = __int_as_float(p2.y), w3 = __int_as_float(p3.y);
            ax = fmaf(v0.x, w0, ax); ay = fmaf(v0.y, w0, ay);
            az = fmaf(v0.z, w0, az); aw = fmaf(v0.w, w0, aw);
            ax = fmaf(v1.x, w1, ax); ay = fmaf(v1.y, w1, ay);
            az = fmaf(v1.z, w1, az); aw = fmaf(v1.w, w1, aw);
            ax = fmaf(v2.x, w2, ax); ay = fmaf(v2.y, w2, ay);
            az = fmaf(v2.z, w2, az); aw = fmaf(v2.w, w2, aw);
            ax = fmaf(v3.x, w3, ax); ay = fmaf(v3.y, w3, ay);
            az = fmaf(v3.z, w3, az); aw = fmaf(v3.w, w3, aw);
        }
        if (e + 4 < end) {   // mid: 2 in flight
            int2 p0 = csr[e];
            int2 p1 = csr[e + 4];
            const float4 v0 = *reinterpret_cast<const float4*>(feat + (size_t)p0.x * IN_F + sub * 4);
            const float4 v1 = *reinterpret_cast<const float4*>(feat + (size_t)p1.x * IN_F + sub * 4);
            float w0 = __int_as_float(p0.y), w1 = __int_as_float(p1.y);
            ax = fmaf(v0.x, w0, ax); ay = fmaf(v0.y, w0, ay);
            az = fmaf(v0.z, w0, az); aw = fmaf(v0.w, w0, aw);
            ax = fmaf(v1.x, w1, ax); ay = fmaf(v1.y, w1, ay);
            az = fmaf(v1.z, w1, az); aw = fmaf(v1.w, w1, aw);
            e += 8;
        }
        if (e < end) {       // tail: 1
            int2 p = csr[e];
            const float4 v = *reinterpret_cast<const float4*>(feat + (size_t)p.x * IN_F + sub * 4);
            float w = __int_as_float(p.y);
            ax = fmaf(v.x, w, ax); ay = fmaf(v.y, w, ay);
            az = fmaf(v.z, w, az); aw = fmaf(v.w, w, aw);
        }

        // combine the 4 edge groups
        ax += __shfl_xor(ax, 16); ax += __shfl_xor(ax, 32);
        ay += __shfl_xor(ay, 16); ay += __shfl_xor(ay, 32);
        az += __shfl_xor(az, 16); az += __shfl_xor(az, 32);
        aw += __shfl_xor(aw, 16); aw += __shfl_xor(aw, 32);

        float invd = 1.0f / (float)max(end - start, 1);
        ax *= invd; ay *= invd; az *= invd; aw *= invd;

        __builtin_amdgcn_wave_barrier();   // don't hoist writes above prior reads
        if (lane < 16)
            *reinterpret_cast<float4*>(&hrow[wave][sub * 4]) = make_float4(ax, ay, az, aw);
        frow[wave][lane] = f;
        __builtin_amdgcn_s_waitcnt(0);     // wave-synchronous LDS publish
        __builtin_amdgcn_wave_barrier();

        float r = bias;
        #pragma unroll
        for (int q = 0; q < 16; ++q) {     // b128 same-address broadcasts
            float4 fv = *reinterpret_cast<const float4*>(&frow[wave][q * 4]);
            float4 hv = *reinterpret_cast<const float4*>(&hrow[wave][q * 4]);
            r = fmaf(fv.x, wsc[4 * q + 0], r);
            r = fmaf(fv.y, wsc[4 * q + 1], r);
            r = fmaf(fv.z, wsc[4 * q + 2], r);
            r = fmaf(fv.w, wsc[4 * q + 3], r);
            r = fmaf(hv.x, wnc[4 * q + 0], r);
            r = fmaf(hv.y, wnc[4 * q + 1], r);
            r = fmaf(hv.z, wnc[4 * q + 2], r);
            r = fmaf(hv.w, wnc[4 * q + 3], r);
        }
        out[(size_t)n * IN_F + lane] = r;
        __builtin_amdgcn_wave_barrier();   // keep next iter's writes below reads
    }
}

// ===========================================================================
// Fallback path (atomic scatter) — used only if ws_size is too small.
// ===========================================================================
__global__ __launch_bounds__(256) void edge_scatter_kernel(
    const float* __restrict__ feat, const float* __restrict__ e_feat,
    const int* __restrict__ src, const int* __restrict__ dst,
    float* __restrict__ neigh, int* __restrict__ deg, int nE)
{
    int t = blockIdx.x * blockDim.x + threadIdx.x;
    int e = t >> 4;
    if (e >= nE) return;
    int sub = t & 15;
    int s = src[e], d = dst[e];
    float w = e_feat[e];
    const float4 v = *reinterpret_cast<const float4*>(feat + (size_t)s * IN_F + sub * 4);
    float* p = neigh + (size_t)d * IN_F + sub * 4;
    atomicAdd(p + 0, v.x * w);
    atomicAdd(p + 1, v.y * w);
    atomicAdd(p + 2, v.z * w);
    atomicAdd(p + 3, v.w * w);
    if (sub == 0) atomicAdd(deg + d, 1);
}

__global__ __launch_bounds__(256) void node_kernel(
    const float* __restrict__ feat,
    const float* __restrict__ W_self, const float* __restrict__ b_self,
    const float* __restrict__ W_neigh, const float* __restrict__ b_neigh,
    const int* __restrict__ deg,
    float* __restrict__ out, int nN)
{
    __shared__ float Ws[IN_F * WPAD];
    __shared__ float Wn[IN_F * WPAD];
    __shared__ float frow[4][IN_F];
    __shared__ float hrow[4][IN_F];
    int tid = threadIdx.x;
    for (int idx = tid; idx < IN_F * OUT_F; idx += 256) {
        int o = idx >> 6, i = idx & 63;
        Ws[i * WPAD + o] = W_self[o * IN_F + i];
        Wn[i * WPAD + o] = W_neigh[o * IN_F + i];
    }
    __syncthreads();
    int wave = tid >> 6, lane = tid & 63;
    int n = blockIdx.x * 4 + wave;
    if (n >= nN) return;
    float f  = feat[(size_t)n * IN_F + lane];
    float ns = out[(size_t)n * IN_F + lane];
    float invd = 1.0f / (float)max(deg[n], 1);
    frow[wave][lane] = f;
    hrow[wave][lane] = ns * invd;
    __builtin_amdgcn_s_waitcnt(0);
    __builtin_amdgcn_wave_barrier();
    float acc = b_self[lane] + b_neigh[lane];
    #pragma unroll
    for (int i = 0; i < IN_F; ++i) {
        acc = fmaf(frow[wave][i], Ws[i * WPAD + lane], acc);
        acc = fmaf(hrow[wave][i], Wn[i * WPAD + lane], acc);
    }
    out[(size_t)n * IN_F + lane] = acc;
}

extern "C" void kernel_launch(void* const* d_in, const int* in_sizes, int n_in,
                              void* d_out, int out_size, void* d_ws, size_t ws_size,
                              hipStream_t stream) {
    const float* feat    = (const float*)d_in[0];
    const float* e_feat  = (const float*)d_in[1];
    const int*   src     = (const int*)d_in[2];
    const int*   dst     = (const int*)d_in[3];
    const float* W_self  = (const float*)d_in[4];
    const float* b_self  = (const float*)d_in[5];
    const float* W_neigh = (const float*)d_in[6];
    const float* b_neigh = (const float*)d_in[7];

    int nN = in_sizes[0] / IN_F;    // 100000
    int nE = in_sizes[2];           // 1600000

    float* out = (float*)d_out;

    size_t cursor_bytes = ((size_t)nN * sizeof(int) + 15) & ~(size_t)15;
    size_t need = cursor_bytes + (size_t)nE * sizeof(int2);

    if (ws_size >= need) {
        // ---- CSR path ----
        int*  cursor   = (int*)d_ws;
        int2* csr      = (int2*)((char*)d_ws + cursor_bytes);
        int*  partials = (int*)csr;   // alias: used only BEFORE csr is written

        int nB = (nN + 1023) / 1024;  // 98 <= 1024
        int nT4 = (nE + 3) / 4;       // 4 edges per thread

        hipMemsetAsync(cursor, 0, (size_t)nN * sizeof(int), stream);
        deg_hist_kernel<<<(nT4 + 255) / 256, 256, 0, stream>>>(dst, cursor, nE);
        scan_block_kernel<<<nB, 1024, 0, stream>>>(cursor, partials, nN);
        scan_partials_kernel<<<1, 1024, 0, stream>>>(partials, nB);
        scan_add_kernel<<<nB, 1024, 0, stream>>>(cursor, partials, nN);
        scatter_kernel<<<(nT4 + 255) / 256, 256, 0, stream>>>(src, dst, e_feat,
                                                              cursor, csr, nE);
        // 1024 blocks x 4 waves; each wave a contiguous chunk of nodes
        int totalWaves = 1024 * 4;
        int chunk = (nN + totalWaves - 1) / totalWaves;   // 25
        node_fused_kernel<<<1024, 256, 0, stream>>>(
            feat, csr, cursor, W_self, b_self, W_neigh, b_neigh, out, nN, chunk);
    } else {
        // ---- fallback atomic path ----
        int* deg = (int*)d_ws;
        hipMemsetAsync(out, 0, (size_t)nN * OUT_F * sizeof(float), stream);
        hipMemsetAsync(deg, 0, (size_t)nN * sizeof(int), stream);
        long long threads = (long long)nE * 16;
        edge_scatter_kernel<<<(int)((threads + 255) / 256), 256, 0, stream>>>(
            feat, e_feat, src, dst, out, deg, nE);
        node_kernel<<<(nN + 3) / 4, 256, 0, stream>>>(
            feat, W_self, b_self, W_neigh, b_neigh, deg, out, nN);
    }
}

// Round 6
// 336.782 us; speedup vs baseline: 1.0100x; 1.0100x over previous
//
#include <hip/hip_runtime.h>

#define IN_F 64
#define OUT_F 64
#define WPAD 65   // padded LDS stride: 2-way bank aliasing = free both directions

// ===========================================================================
// CSR build: counting sort by dst (hist -> scan -> scatter). Unchanged.
// ===========================================================================

__global__ __launch_bounds__(256) void deg_hist_kernel(
    const int* __restrict__ dst, int* __restrict__ cnt, int nE)
{
    int i = blockIdx.x * blockDim.x + threadIdx.x;
    int e0 = i * 4;
    if (e0 + 3 < nE) {
        int4 d = *reinterpret_cast<const int4*>(dst + e0);
        atomicAdd(cnt + d.x, 1); atomicAdd(cnt + d.y, 1);
        atomicAdd(cnt + d.z, 1); atomicAdd(cnt + d.w, 1);
    } else {
        for (int e = e0; e < nE; ++e) atomicAdd(cnt + dst[e], 1);
    }
}

__global__ __launch_bounds__(1024) void scan_block_kernel(
    int* __restrict__ c, int* __restrict__ partials, int nN)
{
    __shared__ int buf[1024];
    int t = threadIdx.x;
    int gid = blockIdx.x * 1024 + t;
    int v = (gid < nN) ? c[gid] : 0;
    buf[t] = v;
    __syncthreads();
    for (int off = 1; off < 1024; off <<= 1) {
        int u = (t >= off) ? buf[t - off] : 0;
        __syncthreads();
        buf[t] += u;
        __syncthreads();
    }
    if (gid < nN) c[gid] = buf[t] - v;            // exclusive
    if (t == 1023) partials[blockIdx.x] = buf[t]; // inclusive block total
}

__global__ __launch_bounds__(1024) void scan_partials_kernel(
    int* __restrict__ p, int nP)
{
    __shared__ int buf[1024];
    int t = threadIdx.x;
    int v = (t < nP) ? p[t] : 0;
    buf[t] = v;
    __syncthreads();
    for (int off = 1; off < 1024; off <<= 1) {
        int u = (t >= off) ? buf[t - off] : 0;
        __syncthreads();
        buf[t] += u;
        __syncthreads();
    }
    if (t < nP) p[t] = buf[t] - v;
}

__global__ __launch_bounds__(1024) void scan_add_kernel(
    int* __restrict__ c, const int* __restrict__ p, int nN)
{
    int gid = blockIdx.x * 1024 + threadIdx.x;
    if (gid < nN) c[gid] += p[blockIdx.x];
}

__global__ __launch_bounds__(256) void scatter_kernel(
    const int* __restrict__ src, const int* __restrict__ dst,
    const float* __restrict__ ef, int* __restrict__ cursor,
    int2* __restrict__ csr, int nE)
{
    int i = blockIdx.x * blockDim.x + threadIdx.x;
    int e0 = i * 4;
    if (e0 + 3 < nE) {
        int4   s = *reinterpret_cast<const int4*>(src + e0);
        int4   d = *reinterpret_cast<const int4*>(dst + e0);
        float4 w = *reinterpret_cast<const float4*>(ef + e0);
        int p0 = atomicAdd(cursor + d.x, 1); csr[p0] = make_int2(s.x, __float_as_int(w.x));
        int p1 = atomicAdd(cursor + d.y, 1); csr[p1] = make_int2(s.y, __float_as_int(w.y));
        int p2 = atomicAdd(cursor + d.z, 1); csr[p2] = make_int2(s.z, __float_as_int(w.z));
        int p3 = atomicAdd(cursor + d.w, 1); csr[p3] = make_int2(s.w, __float_as_int(w.w));
    } else {
        for (int e = e0; e < nE; ++e) {
            int d = dst[e];
            int pos = atomicAdd(cursor + d, 1);
            csr[pos] = make_int2(src[e], __float_as_int(ef[e]));
        }
    }
}

// ===========================================================================
// Phase G: gather+mean ONLY. One wave per node, no LDS, no weights.
// launch_bounds(256,8) forces VGPR<=64 -> 8 waves/SIMD for max outstanding
// gathers (latency-bound phase). h row written to hout (= d_out).
// ===========================================================================
__global__ __launch_bounds__(256, 8) void gather_kernel(
    const float* __restrict__ feat, const int2* __restrict__ csr,
    const int* __restrict__ cursor, float* __restrict__ hout, int nN)
{
    int wave = threadIdx.x >> 6, lane = threadIdx.x & 63;
    int n = blockIdx.x * 4 + wave;
    if (n >= nN) return;

    int start = (n == 0) ? 0 : cursor[n - 1];
    int end   = cursor[n];

    int g   = lane >> 4;    // edge group 0..3
    int sub = lane & 15;    // float4 slot
    float ax = 0.f, ay = 0.f, az = 0.f, aw = 0.f;

    int e = start + g;
    for (; e + 12 < end; e += 16) {          // 4 gathers in flight per lane
        int2 p0 = csr[e];
        int2 p1 = csr[e + 4];
        int2 p2 = csr[e + 8];
        int2 p3 = csr[e + 12];
        const float4 v0 = *reinterpret_cast<const float4*>(feat + (size_t)p0.x * IN_F + sub * 4);
        const float4 v1 = *reinterpret_cast<const float4*>(feat + (size_t)p1.x * IN_F + sub * 4);
        const float4 v2 = *reinterpret_cast<const float4*>(feat + (size_t)p2.x * IN_F + sub * 4);
        const float4 v3 = *reinterpret_cast<const float4*>(feat + (size_t)p3.x * IN_F + sub * 4);
        float w0 = __int_as_float(p0.y), w1 = __int_as_float(p1.y);
        float w2 = __int_as_float(p2.y), w3 = __int_as_float(p3.y);
        ax = fmaf(v0.x, w0, ax); ay = fmaf(v0.y, w0, ay);
        az = fmaf(v0.z, w0, az); aw = fmaf(v0.w, w0, aw);
        ax = fmaf(v1.x, w1, ax); ay = fmaf(v1.y, w1, ay);
        az = fmaf(v1.z, w1, az); aw = fmaf(v1.w, w1, aw);
        ax = fmaf(v2.x, w2, ax); ay = fmaf(v2.y, w2, ay);
        az = fmaf(v2.z, w2, az); aw = fmaf(v2.w, w2, aw);
        ax = fmaf(v3.x, w3, ax); ay = fmaf(v3.y, w3, ay);
        az = fmaf(v3.z, w3, az); aw = fmaf(v3.w, w3, aw);
    }
    if (e + 4 < end) {                        // 2 in flight
        int2 p0 = csr[e];
        int2 p1 = csr[e + 4];
        const float4 v0 = *reinterpret_cast<const float4*>(feat + (size_t)p0.x * IN_F + sub * 4);
        const float4 v1 = *reinterpret_cast<const float4*>(feat + (size_t)p1.x * IN_F + sub * 4);
        float w0 = __int_as_float(p0.y), w1 = __int_as_float(p1.y);
        ax = fmaf(v0.x, w0, ax); ay = fmaf(v0.y, w0, ay);
        az = fmaf(v0.z, w0, az); aw = fmaf(v0.w, w0, aw);
        ax = fmaf(v1.x, w1, ax); ay = fmaf(v1.y, w1, ay);
        az = fmaf(v1.z, w1, az); aw = fmaf(v1.w, w1, aw);
        e += 8;
    }
    if (e < end) {
        int2 p = csr[e];
        const float4 v = *reinterpret_cast<const float4*>(feat + (size_t)p.x * IN_F + sub * 4);
        float w = __int_as_float(p.y);
        ax = fmaf(v.x, w, ax); ay = fmaf(v.y, w, ay);
        az = fmaf(v.z, w, az); aw = fmaf(v.w, w, aw);
    }

    ax += __shfl_xor(ax, 16); ax += __shfl_xor(ax, 32);
    ay += __shfl_xor(ay, 16); ay += __shfl_xor(ay, 32);
    az += __shfl_xor(az, 16); az += __shfl_xor(az, 32);
    aw += __shfl_xor(aw, 16); aw += __shfl_xor(aw, 32);

    float invd = 1.0f / (float)max(end - start, 1);
    if (lane < 16) {
        float4 hv = make_float4(ax * invd, ay * invd, az * invd, aw * invd);
        *reinterpret_cast<float4*>(hout + (size_t)n * IN_F + sub * 4) = hv;
    }
}

// ===========================================================================
// Phase T: out = feat·Ws^T + h·Wn^T + bias, in place (h lives in out rows).
// Weights register-pinned: single reused LDS buffer is OVERWRITTEN between
// extractions, so the compiler cannot re-fold wsc reads into LDS — it must
// keep them in VGPRs (expect VGPR_Count >= 160).
// ===========================================================================
__global__ __launch_bounds__(256, 2) void transform_kernel(
    const float* __restrict__ feat,
    const float* __restrict__ W_self, const float* __restrict__ b_self,
    const float* __restrict__ W_neigh, const float* __restrict__ b_neigh,
    float* __restrict__ out, int nN, int chunk)
{
    __shared__ float Wbuf[IN_F * WPAD];
    __shared__ float frow[4][IN_F];
    __shared__ float hrow[4][IN_F];

    int tid = threadIdx.x;
    int wave = tid >> 6, lane = tid & 63;

    // stage W_self transposed -> extract per-lane row of W_self
    for (int idx = tid; idx < IN_F * OUT_F; idx += 256) {
        int o = idx >> 6, i = idx & 63;
        Wbuf[i * WPAD + o] = W_self[idx];      // coalesced global read
    }
    __syncthreads();
    float wsc[IN_F];
    #pragma unroll
    for (int i = 0; i < IN_F; ++i) wsc[i] = Wbuf[i * WPAD + lane];  // = W_self[lane][i]
    __syncthreads();                            // all reads done before overwrite
    for (int idx = tid; idx < IN_F * OUT_F; idx += 256) {
        int o = idx >> 6, i = idx & 63;
        Wbuf[i * WPAD + o] = W_neigh[idx];
    }
    __syncthreads();
    float wnc[IN_F];
    #pragma unroll
    for (int i = 0; i < IN_F; ++i) wnc[i] = Wbuf[i * WPAD + lane];  // = W_neigh[lane][i]

    float bias = b_self[lane] + b_neigh[lane];

    int wid = blockIdx.x * 4 + wave;
    int n0 = wid * chunk;
    int n1 = min(n0 + chunk, nN);
    // no __syncthreads below -> early exit safe
    for (int n = n0; n < n1; ++n) {
        float f = feat[(size_t)n * IN_F + lane];
        float h = out[(size_t)n * IN_F + lane];
        __builtin_amdgcn_wave_barrier();       // writes stay below prior reads
        frow[wave][lane] = f;
        hrow[wave][lane] = h;
        __builtin_amdgcn_s_waitcnt(0);         // wave-synchronous LDS publish
        __builtin_amdgcn_wave_barrier();

        float r0 = bias, r1 = 0.f;             // 2 accumulators: split dep chain
        #pragma unroll
        for (int q = 0; q < 16; ++q) {         // b128 same-address broadcasts
            float4 fv = *reinterpret_cast<const float4*>(&frow[wave][q * 4]);
            float4 hv = *reinterpret_cast<const float4*>(&hrow[wave][q * 4]);
            r0 = fmaf(fv.x, wsc[4 * q + 0], r0);
            r1 = fmaf(hv.x, wnc[4 * q + 0], r1);
            r0 = fmaf(fv.y, wsc[4 * q + 1], r0);
            r1 = fmaf(hv.y, wnc[4 * q + 1], r1);
            r0 = fmaf(fv.z, wsc[4 * q + 2], r0);
            r1 = fmaf(hv.z, wnc[4 * q + 2], r1);
            r0 = fmaf(fv.w, wsc[4 * q + 3], r0);
            r1 = fmaf(hv.w, wnc[4 * q + 3], r1);
        }
        out[(size_t)n * IN_F + lane] = r0 + r1;
        __builtin_amdgcn_wave_barrier();
    }
}

// ===========================================================================
// Fallback path (atomic scatter) — used only if ws_size is too small.
// ===========================================================================
__global__ __launch_bounds__(256) void edge_scatter_kernel(
    const float* __restrict__ feat, const float* __restrict__ e_feat,
    const int* __restrict__ src, const int* __restrict__ dst,
    float* __restrict__ neigh, int* __restrict__ deg, int nE)
{
    int t = blockIdx.x * blockDim.x + threadIdx.x;
    int e = t >> 4;
    if (e >= nE) return;
    int sub = t & 15;
    int s = src[e], d = dst[e];
    float w = e_feat[e];
    const float4 v = *reinterpret_cast<const float4*>(feat + (size_t)s * IN_F + sub * 4);
    float* p = neigh + (size_t)d * IN_F + sub * 4;
    atomicAdd(p + 0, v.x * w);
    atomicAdd(p + 1, v.y * w);
    atomicAdd(p + 2, v.z * w);
    atomicAdd(p + 3, v.w * w);
    if (sub == 0) atomicAdd(deg + d, 1);
}

__global__ __launch_bounds__(256) void node_kernel(
    const float* __restrict__ feat,
    const float* __restrict__ W_self, const float* __restrict__ b_self,
    const float* __restrict__ W_neigh, const float* __restrict__ b_neigh,
    const int* __restrict__ deg,
    float* __restrict__ out, int nN)
{
    __shared__ float Ws[IN_F * WPAD];
    __shared__ float Wn[IN_F * WPAD];
    __shared__ float frow[4][IN_F];
    __shared__ float hrow[4][IN_F];
    int tid = threadIdx.x;
    for (int idx = tid; idx < IN_F * OUT_F; idx += 256) {
        int o = idx >> 6, i = idx & 63;
        Ws[i * WPAD + o] = W_self[o * IN_F + i];
        Wn[i * WPAD + o] = W_neigh[o * IN_F + i];
    }
    __syncthreads();
    int wave = tid >> 6, lane = tid & 63;
    int n = blockIdx.x * 4 + wave;
    if (n >= nN) return;
    float f  = feat[(size_t)n * IN_F + lane];
    float ns = out[(size_t)n * IN_F + lane];
    float invd = 1.0f / (float)max(deg[n], 1);
    frow[wave][lane] = f;
    hrow[wave][lane] = ns * invd;
    __builtin_amdgcn_s_waitcnt(0);
    __builtin_amdgcn_wave_barrier();
    float acc = b_self[lane] + b_neigh[lane];
    #pragma unroll
    for (int i = 0; i < IN_F; ++i) {
        acc = fmaf(frow[wave][i], Ws[i * WPAD + lane], acc);
        acc = fmaf(hrow[wave][i], Wn[i * WPAD + lane], acc);
    }
    out[(size_t)n * IN_F + lane] = acc;
}

extern "C" void kernel_launch(void* const* d_in, const int* in_sizes, int n_in,
                              void* d_out, int out_size, void* d_ws, size_t ws_size,
                              hipStream_t stream) {
    const float* feat    = (const float*)d_in[0];
    const float* e_feat  = (const float*)d_in[1];
    const int*   src     = (const int*)d_in[2];
    const int*   dst     = (const int*)d_in[3];
    const float* W_self  = (const float*)d_in[4];
    const float* b_self  = (const float*)d_in[5];
    const float* W_neigh = (const float*)d_in[6];
    const float* b_neigh = (const float*)d_in[7];

    int nN = in_sizes[0] / IN_F;    // 100000
    int nE = in_sizes[2];           // 1600000

    float* out = (float*)d_out;

    size_t cursor_bytes = ((size_t)nN * sizeof(int) + 15) & ~(size_t)15;
    size_t need = cursor_bytes + (size_t)nE * sizeof(int2);

    if (ws_size >= need) {
        // ---- CSR path ----
        int*  cursor   = (int*)d_ws;
        int2* csr      = (int2*)((char*)d_ws + cursor_bytes);
        int*  partials = (int*)csr;   // alias: used only BEFORE csr is written

        int nB = (nN + 1023) / 1024;  // 98 <= 1024
        int nT4 = (nE + 3) / 4;       // 4 edges per thread

        hipMemsetAsync(cursor, 0, (size_t)nN * sizeof(int), stream);
        deg_hist_kernel<<<(nT4 + 255) / 256, 256, 0, stream>>>(dst, cursor, nE);
        scan_block_kernel<<<nB, 1024, 0, stream>>>(cursor, partials, nN);
        scan_partials_kernel<<<1, 1024, 0, stream>>>(partials, nB);
        scan_add_kernel<<<nB, 1024, 0, stream>>>(cursor, partials, nN);
        scatter_kernel<<<(nT4 + 255) / 256, 256, 0, stream>>>(src, dst, e_feat,
                                                              cursor, csr, nE);
        // Phase G: gather+mean -> h rows in d_out. One wave per node.
        gather_kernel<<<(nN + 3) / 4, 256, 0, stream>>>(feat, csr, cursor, out, nN);
        // Phase T: dual GEMV, in place. 1280 blocks x 4 waves, chunked.
        int totalWaves = 1280 * 4;
        int chunk = (nN + totalWaves - 1) / totalWaves;   // 20
        transform_kernel<<<1280, 256, 0, stream>>>(
            feat, W_self, b_self, W_neigh, b_neigh, out, nN, chunk);
    } else {
        // ---- fallback atomic path ----
        int* deg = (int*)d_ws;
        hipMemsetAsync(out, 0, (size_t)nN * OUT_F * sizeof(float), stream);
        hipMemsetAsync(deg, 0, (size_t)nN * sizeof(int), stream);
        long long threads = (long long)nE * 16;
        edge_scatter_kernel<<<(int)((threads + 255) / 256), 256, 0, stream>>>(
            feat, e_feat, src, dst, out, deg, nE);
        node_kernel<<<(nN + 3) / 4, 256, 0, stream>>>(
            feat, W_self, b_self, W_neigh, b_neigh, deg, out, nN);
    }
}

// Round 7
// 240.116 us; speedup vs baseline: 1.4165x; 1.4026x over previous
//
#include <hip/hip_runtime.h>

#define IN_F 64
#define OUT_F 64
#define WPAD 65   // padded LDS stride: 2-way bank aliasing = free both directions

// ===========================================================================
// CSR build, rank tier: hist returns per-edge rank -> scatter has NO atomics.
// ===========================================================================

// K1r: degree histogram + per-edge rank (rank = atomicAdd return value)
__global__ __launch_bounds__(256) void deg_hist_rank_kernel(
    const int* __restrict__ dst, int* __restrict__ cnt,
    int* __restrict__ rank, int nE)
{
    int i = blockIdx.x * blockDim.x + threadIdx.x;
    int e0 = i * 4;
    if (e0 + 3 < nE) {
        int4 d = *reinterpret_cast<const int4*>(dst + e0);
        int4 r;
        r.x = atomicAdd(cnt + d.x, 1);
        r.y = atomicAdd(cnt + d.y, 1);
        r.z = atomicAdd(cnt + d.z, 1);
        r.w = atomicAdd(cnt + d.w, 1);
        *reinterpret_cast<int4*>(rank + e0) = r;   // coalesced
    } else {
        for (int e = e0; e < nE; ++e) rank[e] = atomicAdd(cnt + dst[e], 1);
    }
}

// K1m: plain histogram (mid tier)
__global__ __launch_bounds__(256) void deg_hist_kernel(
    const int* __restrict__ dst, int* __restrict__ cnt, int nE)
{
    int i = blockIdx.x * blockDim.x + threadIdx.x;
    int e0 = i * 4;
    if (e0 + 3 < nE) {
        int4 d = *reinterpret_cast<const int4*>(dst + e0);
        atomicAdd(cnt + d.x, 1); atomicAdd(cnt + d.y, 1);
        atomicAdd(cnt + d.z, 1); atomicAdd(cnt + d.w, 1);
    } else {
        for (int e = e0; e < nE; ++e) atomicAdd(cnt + dst[e], 1);
    }
}

// K2a/b/c: exclusive scan (block -> partials -> add-back)
__global__ __launch_bounds__(1024) void scan_block_kernel(
    int* __restrict__ c, int* __restrict__ partials, int nN)
{
    __shared__ int buf[1024];
    int t = threadIdx.x;
    int gid = blockIdx.x * 1024 + t;
    int v = (gid < nN) ? c[gid] : 0;
    buf[t] = v;
    __syncthreads();
    for (int off = 1; off < 1024; off <<= 1) {
        int u = (t >= off) ? buf[t - off] : 0;
        __syncthreads();
        buf[t] += u;
        __syncthreads();
    }
    if (gid < nN) c[gid] = buf[t] - v;            // exclusive
    if (t == 1023) partials[blockIdx.x] = buf[t]; // inclusive block total
}

__global__ __launch_bounds__(1024) void scan_partials_kernel(
    int* __restrict__ p, int nP)
{
    __shared__ int buf[1024];
    int t = threadIdx.x;
    int v = (t < nP) ? p[t] : 0;
    buf[t] = v;
    __syncthreads();
    for (int off = 1; off < 1024; off <<= 1) {
        int u = (t >= off) ? buf[t - off] : 0;
        __syncthreads();
        buf[t] += u;
        __syncthreads();
    }
    if (t < nP) p[t] = buf[t] - v;
}

__global__ __launch_bounds__(1024) void scan_add_kernel(
    int* __restrict__ c, const int* __restrict__ p, int nN)
{
    int gid = blockIdx.x * 1024 + threadIdx.x;
    if (gid < nN) c[gid] += p[blockIdx.x];
}

// K3r: atomic-free scatter. pos = offs[d] + rank[e]; offs never mutated.
__global__ __launch_bounds__(256) void scatter_rank_kernel(
    const int* __restrict__ src, const int* __restrict__ dst,
    const float* __restrict__ ef, const int* __restrict__ rank,
    const int* __restrict__ offs, int2* __restrict__ csr, int nE)
{
    int i = blockIdx.x * blockDim.x + threadIdx.x;
    int e0 = i * 4;
    if (e0 + 3 < nE) {
        int4   s = *reinterpret_cast<const int4*>(src + e0);
        int4   d = *reinterpret_cast<const int4*>(dst + e0);
        int4   r = *reinterpret_cast<const int4*>(rank + e0);
        float4 w = *reinterpret_cast<const float4*>(ef + e0);
        // offs[d.*]: random 4B reads in a 400 KB table (L2-hot), independent
        int p0 = offs[d.x] + r.x;
        int p1 = offs[d.y] + r.y;
        int p2 = offs[d.z] + r.z;
        int p3 = offs[d.w] + r.w;
        csr[p0] = make_int2(s.x, __float_as_int(w.x));
        csr[p1] = make_int2(s.y, __float_as_int(w.y));
        csr[p2] = make_int2(s.z, __float_as_int(w.z));
        csr[p3] = make_int2(s.w, __float_as_int(w.w));
    } else {
        for (int e = e0; e < nE; ++e) {
            int pos = offs[dst[e]] + rank[e];
            csr[pos] = make_int2(src[e], __float_as_int(ef[e]));
        }
    }
}

// K3m: atomic scatter (mid tier; cursor becomes inclusive ends)
__global__ __launch_bounds__(256) void scatter_kernel(
    const int* __restrict__ src, const int* __restrict__ dst,
    const float* __restrict__ ef, int* __restrict__ cursor,
    int2* __restrict__ csr, int nE)
{
    int i = blockIdx.x * blockDim.x + threadIdx.x;
    int e0 = i * 4;
    if (e0 + 3 < nE) {
        int4   s = *reinterpret_cast<const int4*>(src + e0);
        int4   d = *reinterpret_cast<const int4*>(dst + e0);
        float4 w = *reinterpret_cast<const float4*>(ef + e0);
        int p0 = atomicAdd(cursor + d.x, 1); csr[p0] = make_int2(s.x, __float_as_int(w.x));
        int p1 = atomicAdd(cursor + d.y, 1); csr[p1] = make_int2(s.y, __float_as_int(w.y));
        int p2 = atomicAdd(cursor + d.z, 1); csr[p2] = make_int2(s.z, __float_as_int(w.z));
        int p3 = atomicAdd(cursor + d.w, 1); csr[p3] = make_int2(s.w, __float_as_int(w.w));
    } else {
        for (int e = e0; e < nE; ++e) {
            int d = dst[e];
            int pos = atomicAdd(cursor + d, 1);
            csr[pos] = make_int2(src[e], __float_as_int(ef[e]));
        }
    }
}

// ===========================================================================
// Phase G: gather+mean. One wave per node, no LDS/weights; VGPR<=64 via
// launch_bounds(256,8). inc_mode: 1 = c[] holds inclusive ends (mid tier),
// 0 = c[] holds exclusive offsets (rank tier).
// ===========================================================================
__global__ __launch_bounds__(256, 8) void gather_kernel(
    const float* __restrict__ feat, const int2* __restrict__ csr,
    const int* __restrict__ c, float* __restrict__ hout,
    int nN, int nE, int inc_mode)
{
    int wave = threadIdx.x >> 6, lane = threadIdx.x & 63;
    int n = blockIdx.x * 4 + wave;
    if (n >= nN) return;

    int start, end;
    if (inc_mode) { start = (n == 0) ? 0 : c[n - 1]; end = c[n]; }
    else          { start = c[n]; end = (n + 1 < nN) ? c[n + 1] : nE; }

    int g   = lane >> 4;    // edge group 0..3
    int sub = lane & 15;    // float4 slot
    float ax = 0.f, ay = 0.f, az = 0.f, aw = 0.f;

    int e = start + g;
    for (; e + 12 < end; e += 16) {          // 4 gathers in flight per lane
        int2 p0 = csr[e];
        int2 p1 = csr[e + 4];
        int2 p2 = csr[e + 8];
        int2 p3 = csr[e + 12];
        const float4 v0 = *reinterpret_cast<const float4*>(feat + (size_t)p0.x * IN_F + sub * 4);
        const float4 v1 = *reinterpret_cast<const float4*>(feat + (size_t)p1.x * IN_F + sub * 4);
        const float4 v2 = *reinterpret_cast<const float4*>(feat + (size_t)p2.x * IN_F + sub * 4);
        const float4 v3 = *reinterpret_cast<const float4*>(feat + (size_t)p3.x * IN_F + sub * 4);
        float w0 = __int_as_float(p0.y), w1 = __int_as_float(p1.y);
        float w2 = __int_as_float(p2.y), w3 = __int_as_float(p3.y);
        ax = fmaf(v0.x, w0, ax); ay = fmaf(v0.y, w0, ay);
        az = fmaf(v0.z, w0, az); aw = fmaf(v0.w, w0, aw);
        ax = fmaf(v1.x, w1, ax); ay = fmaf(v1.y, w1, ay);
        az = fmaf(v1.z, w1, az); aw = fmaf(v1.w, w1, aw);
        ax = fmaf(v2.x, w2, ax); ay = fmaf(v2.y, w2, ay);
        az = fmaf(v2.z, w2, az); aw = fmaf(v2.w, w2, aw);
        ax = fmaf(v3.x, w3, ax); ay = fmaf(v3.y, w3, ay);
        az = fmaf(v3.z, w3, az); aw = fmaf(v3.w, w3, aw);
    }
    if (e + 4 < end) {                        // 2 in flight
        int2 p0 = csr[e];
        int2 p1 = csr[e + 4];
        const float4 v0 = *reinterpret_cast<const float4*>(feat + (size_t)p0.x * IN_F + sub * 4);
        const float4 v1 = *reinterpret_cast<const float4*>(feat + (size_t)p1.x * IN_F + sub * 4);
        float w0 = __int_as_float(p0.y), w1 = __int_as_float(p1.y);
        ax = fmaf(v0.x, w0, ax); ay = fmaf(v0.y, w0, ay);
        az = fmaf(v0.z, w0, az); aw = fmaf(v0.w, w0, aw);
        ax = fmaf(v1.x, w1, ax); ay = fmaf(v1.y, w1, ay);
        az = fmaf(v1.z, w1, az); aw = fmaf(v1.w, w1, aw);
        e += 8;
    }
    if (e < end) {
        int2 p = csr[e];
        const float4 v = *reinterpret_cast<const float4*>(feat + (size_t)p.x * IN_F + sub * 4);
        float w = __int_as_float(p.y);
        ax = fmaf(v.x, w, ax); ay = fmaf(v.y, w, ay);
        az = fmaf(v.z, w, az); aw = fmaf(v.w, w, aw);
    }

    ax += __shfl_xor(ax, 16); ax += __shfl_xor(ax, 32);
    ay += __shfl_xor(ay, 16); ay += __shfl_xor(ay, 32);
    az += __shfl_xor(az, 16); az += __shfl_xor(az, 32);
    aw += __shfl_xor(aw, 16); aw += __shfl_xor(aw, 32);

    float invd = 1.0f / (float)max(end - start, 1);
    if (lane < 16) {
        float4 hv = make_float4(ax * invd, ay * invd, az * invd, aw * invd);
        *reinterpret_cast<float4*>(hout + (size_t)n * IN_F + sub * 4) = hv;
    }
}

// ===========================================================================
// Phase T: out = feat·Ws^T + h·Wn^T + bias, in place. Weights register-
// pinned via overwritten LDS staging buffer.
// ===========================================================================
__global__ __launch_bounds__(256, 2) void transform_kernel(
    const float* __restrict__ feat,
    const float* __restrict__ W_self, const float* __restrict__ b_self,
    const float* __restrict__ W_neigh, const float* __restrict__ b_neigh,
    float* __restrict__ out, int nN, int chunk)
{
    __shared__ float Wbuf[IN_F * WPAD];
    __shared__ float frow[4][IN_F];
    __shared__ float hrow[4][IN_F];

    int tid = threadIdx.x;
    int wave = tid >> 6, lane = tid & 63;

    for (int idx = tid; idx < IN_F * OUT_F; idx += 256) {
        int o = idx >> 6, i = idx & 63;
        Wbuf[i * WPAD + o] = W_self[idx];
    }
    __syncthreads();
    float wsc[IN_F];
    #pragma unroll
    for (int i = 0; i < IN_F; ++i) wsc[i] = Wbuf[i * WPAD + lane];  // W_self[lane][i]
    __syncthreads();
    for (int idx = tid; idx < IN_F * OUT_F; idx += 256) {
        int o = idx >> 6, i = idx & 63;
        Wbuf[i * WPAD + o] = W_neigh[idx];
    }
    __syncthreads();
    float wnc[IN_F];
    #pragma unroll
    for (int i = 0; i < IN_F; ++i) wnc[i] = Wbuf[i * WPAD + lane];  // W_neigh[lane][i]

    float bias = b_self[lane] + b_neigh[lane];

    int wid = blockIdx.x * 4 + wave;
    int n0 = wid * chunk;
    int n1 = min(n0 + chunk, nN);
    for (int n = n0; n < n1; ++n) {
        float f = feat[(size_t)n * IN_F + lane];
        float h = out[(size_t)n * IN_F + lane];
        __builtin_amdgcn_wave_barrier();
        frow[wave][lane] = f;
        hrow[wave][lane] = h;
        __builtin_amdgcn_s_waitcnt(0);
        __builtin_amdgcn_wave_barrier();

        float r0 = bias, r1 = 0.f;
        #pragma unroll
        for (int q = 0; q < 16; ++q) {
            float4 fv = *reinterpret_cast<const float4*>(&frow[wave][q * 4]);
            float4 hv = *reinterpret_cast<const float4*>(&hrow[wave][q * 4]);
            r0 = fmaf(fv.x, wsc[4 * q + 0], r0);
            r1 = fmaf(hv.x, wnc[4 * q + 0], r1);
            r0 = fmaf(fv.y, wsc[4 * q + 1], r0);
            r1 = fmaf(hv.y, wnc[4 * q + 1], r1);
            r0 = fmaf(fv.z, wsc[4 * q + 2], r0);
            r1 = fmaf(hv.z, wnc[4 * q + 2], r1);
            r0 = fmaf(fv.w, wsc[4 * q + 3], r0);
            r1 = fmaf(hv.w, wnc[4 * q + 3], r1);
        }
        out[(size_t)n * IN_F + lane] = r0 + r1;
        __builtin_amdgcn_wave_barrier();
    }
}

// ===========================================================================
// Last-resort fallback (tiny ws): atomic edge scatter into out.
// ===========================================================================
__global__ __launch_bounds__(256) void edge_scatter_kernel(
    const float* __restrict__ feat, const float* __restrict__ e_feat,
    const int* __restrict__ src, const int* __restrict__ dst,
    float* __restrict__ neigh, int* __restrict__ deg, int nE)
{
    int t = blockIdx.x * blockDim.x + threadIdx.x;
    int e = t >> 4;
    if (e >= nE) return;
    int sub = t & 15;
    int s = src[e], d = dst[e];
    float w = e_feat[e];
    const float4 v = *reinterpret_cast<const float4*>(feat + (size_t)s * IN_F + sub * 4);
    float* p = neigh + (size_t)d * IN_F + sub * 4;
    atomicAdd(p + 0, v.x * w);
    atomicAdd(p + 1, v.y * w);
    atomicAdd(p + 2, v.z * w);
    atomicAdd(p + 3, v.w * w);
    if (sub == 0) atomicAdd(deg + d, 1);
}

__global__ __launch_bounds__(256) void node_kernel(
    const float* __restrict__ feat,
    const float* __restrict__ W_self, const float* __restrict__ b_self,
    const float* __restrict__ W_neigh, const float* __restrict__ b_neigh,
    const int* __restrict__ deg,
    float* __restrict__ out, int nN)
{
    __shared__ float Ws[IN_F * WPAD];
    __shared__ float Wn[IN_F * WPAD];
    __shared__ float frow[4][IN_F];
    __shared__ float hrow[4][IN_F];
    int tid = threadIdx.x;
    for (int idx = tid; idx < IN_F * OUT_F; idx += 256) {
        int o = idx >> 6, i = idx & 63;
        Ws[i * WPAD + o] = W_self[o * IN_F + i];
        Wn[i * WPAD + o] = W_neigh[o * IN_F + i];
    }
    __syncthreads();
    int wave = tid >> 6, lane = tid & 63;
    int n = blockIdx.x * 4 + wave;
    if (n >= nN) return;
    float f  = feat[(size_t)n * IN_F + lane];
    float ns = out[(size_t)n * IN_F + lane];
    float invd = 1.0f / (float)max(deg[n], 1);
    frow[wave][lane] = f;
    hrow[wave][lane] = ns * invd;
    __builtin_amdgcn_s_waitcnt(0);
    __builtin_amdgcn_wave_barrier();
    float acc = b_self[lane] + b_neigh[lane];
    #pragma unroll
    for (int i = 0; i < IN_F; ++i) {
        acc = fmaf(frow[wave][i], Ws[i * WPAD + lane], acc);
        acc = fmaf(hrow[wave][i], Wn[i * WPAD + lane], acc);
    }
    out[(size_t)n * IN_F + lane] = acc;
}

extern "C" void kernel_launch(void* const* d_in, const int* in_sizes, int n_in,
                              void* d_out, int out_size, void* d_ws, size_t ws_size,
                              hipStream_t stream) {
    const float* feat    = (const float*)d_in[0];
    const float* e_feat  = (const float*)d_in[1];
    const int*   src     = (const int*)d_in[2];
    const int*   dst     = (const int*)d_in[3];
    const float* W_self  = (const float*)d_in[4];
    const float* b_self  = (const float*)d_in[5];
    const float* W_neigh = (const float*)d_in[6];
    const float* b_neigh = (const float*)d_in[7];

    int nN = in_sizes[0] / IN_F;    // 100000
    int nE = in_sizes[2];           // 1600000

    float* out = (float*)d_out;

    size_t offs_b = ((size_t)nN * sizeof(int) + 15) & ~(size_t)15;
    size_t rank_b = ((size_t)nE * sizeof(int) + 15) & ~(size_t)15;
    size_t csr_b  = (size_t)nE * sizeof(int2);

    int nB  = (nN + 1023) / 1024;
    int nT4 = (nE + 3) / 4;

    if (ws_size >= offs_b + rank_b + csr_b) {
        // ---- rank tier: atomic-free scatter ----
        int*  offs = (int*)d_ws;
        int*  rank = (int*)((char*)d_ws + offs_b);
        int2* csr  = (int2*)((char*)d_ws + offs_b + rank_b);
        int*  partials = (int*)csr;   // alias: used only BEFORE csr is written

        hipMemsetAsync(offs, 0, (size_t)nN * sizeof(int), stream);
        deg_hist_rank_kernel<<<(nT4 + 255) / 256, 256, 0, stream>>>(dst, offs, rank, nE);
        scan_block_kernel<<<nB, 1024, 0, stream>>>(offs, partials, nN);
        scan_partials_kernel<<<1, 1024, 0, stream>>>(partials, nB);
        scan_add_kernel<<<nB, 1024, 0, stream>>>(offs, partials, nN);
        scatter_rank_kernel<<<(nT4 + 255) / 256, 256, 0, stream>>>(
            src, dst, e_feat, rank, offs, csr, nE);
        gather_kernel<<<(nN + 3) / 4, 256, 0, stream>>>(feat, csr, offs, out,
                                                        nN, nE, 0);
        int totalWaves = 1280 * 4;
        int chunk = (nN + totalWaves - 1) / totalWaves;
        transform_kernel<<<1280, 256, 0, stream>>>(
            feat, W_self, b_self, W_neigh, b_neigh, out, nN, chunk);
    } else if (ws_size >= offs_b + csr_b) {
        // ---- mid tier: atomic scatter ----
        int*  cursor = (int*)d_ws;
        int2* csr    = (int2*)((char*)d_ws + offs_b);
        int*  partials = (int*)csr;

        hipMemsetAsync(cursor, 0, (size_t)nN * sizeof(int), stream);
        deg_hist_kernel<<<(nT4 + 255) / 256, 256, 0, stream>>>(dst, cursor, nE);
        scan_block_kernel<<<nB, 1024, 0, stream>>>(cursor, partials, nN);
        scan_partials_kernel<<<1, 1024, 0, stream>>>(partials, nB);
        scan_add_kernel<<<nB, 1024, 0, stream>>>(cursor, partials, nN);
        scatter_kernel<<<(nT4 + 255) / 256, 256, 0, stream>>>(src, dst, e_feat,
                                                              cursor, csr, nE);
        gather_kernel<<<(nN + 3) / 4, 256, 0, stream>>>(feat, csr, cursor, out,
                                                        nN, nE, 1);
        int totalWaves = 1280 * 4;
        int chunk = (nN + totalWaves - 1) / totalWaves;
        transform_kernel<<<1280, 256, 0, stream>>>(
            feat, W_self, b_self, W_neigh, b_neigh, out, nN, chunk);
    } else {
        // ---- fallback atomic path ----
        int* deg = (int*)d_ws;
        hipMemsetAsync(out, 0, (size_t)nN * OUT_F * sizeof(float), stream);
        hipMemsetAsync(deg, 0, (size_t)nN * sizeof(int), stream);
        long long threads = (long long)nE * 16;
        edge_scatter_kernel<<<(int)((threads + 255) / 256), 256, 0, stream>>>(
            feat, e_feat, src, dst, out, deg, nE);
        node_kernel<<<(nN + 3) / 4, 256, 0, stream>>>(
            feat, W_self, b_self, W_neigh, b_neigh, deg, out, nN);
    }
}